// Round 5
// baseline (159.525 us; speedup 1.0000x reference)
//
#include <hip/hip_runtime.h>
#include <cstdint>
#include <cstddef>

#define N_  16
#define C_  64
#define H_  224
#define W_  224
#define HW_ (H_ * W_)      // 50176
#define NHW_ (N_ * HW_)    // 802816

typedef unsigned long long u64;
typedef float f32x4 __attribute__((ext_vector_type(4)));

// ---------------------------------------------------------------------------
// ws layout (bytes):
//   [0,      16384) double2 part[64*16]   per-(c,n) partial {sum, sumsq}
//   [32768, +6.4MB) u64   abits[16*50176] activation sign bits packed over C
// ---------------------------------------------------------------------------

__global__ void k_stats(const float* __restrict__ x, double2* __restrict__ part) {
    int b = blockIdx.x;          // (n,c)
    int c = b & 63;
    int n = b >> 6;
    const float4* px = (const float4*)(x + (size_t)(n * 64 + c) * HW_);
    double s = 0.0, ss = 0.0;
    for (int i = threadIdx.x; i < HW_ / 4; i += 256) {
        float4 v = px[i];
        s  += (double)v.x + (double)v.y + (double)v.z + (double)v.w;
        ss += (double)v.x * v.x + (double)v.y * v.y
            + (double)v.z * v.z + (double)v.w * v.w;
    }
    __shared__ double sh_s[256];
    __shared__ double sh_q[256];
    sh_s[threadIdx.x] = s;
    sh_q[threadIdx.x] = ss;
    __syncthreads();
    for (int off = 128; off > 0; off >>= 1) {
        if (threadIdx.x < (unsigned)off) {
            sh_s[threadIdx.x] += sh_s[threadIdx.x + off];
            sh_q[threadIdx.x] += sh_q[threadIdx.x + off];
        }
        __syncthreads();
    }
    if (threadIdx.x == 0) part[c * 16 + n] = make_double2(sh_s[0], sh_q[0]);
}

// one thread = 4 consecutive spatial positions, all 64 channels.
// scale/bias computed inline from part (no finalize kernel).
__global__ void k_binpack(const float* __restrict__ x,
                          const double2* __restrict__ part,
                          const float* __restrict__ gamma,
                          const float* __restrict__ beta,
                          u64* __restrict__ abits) {
    __shared__ float s_scale[64];
    __shared__ float s_bias[64];
    int t = threadIdx.x;
    if (t < 64) {
        double s = 0.0, ss = 0.0;
#pragma unroll
        for (int nn = 0; nn < 16; ++nn) {
            double2 p = part[t * 16 + nn];
            s += p.x; ss += p.y;
        }
        double mean = s / (double)NHW_;
        double var  = ss / (double)NHW_ - mean * mean;
        double inv  = 1.0 / sqrt(var + 1e-5);
        double g    = (double)gamma[t];
        s_scale[t] = (float)(g * inv);
        s_bias[t]  = (float)((double)beta[t] - mean * g * inv);
    }
    __syncthreads();
    int p4 = blockIdx.x * 256 + t;             // quad within image, 0..12543
    int n  = blockIdx.y;
    const float* px = x + (size_t)n * 64 * HW_ + (size_t)p4 * 4;

    unsigned lo0 = 0, lo1 = 0, lo2 = 0, lo3 = 0;
    unsigned hi0 = 0, hi1 = 0, hi2 = 0, hi3 = 0;
#pragma unroll 8
    for (int c = 0; c < 32; ++c) {
        float4 v = *(const float4*)(px + (size_t)c * HW_);
        float sc = s_scale[c], bi = s_bias[c];
        lo0 |= (fmaf(v.x, sc, bi) < 0.0f ? 1u : 0u) << c;
        lo1 |= (fmaf(v.y, sc, bi) < 0.0f ? 1u : 0u) << c;
        lo2 |= (fmaf(v.z, sc, bi) < 0.0f ? 1u : 0u) << c;
        lo3 |= (fmaf(v.w, sc, bi) < 0.0f ? 1u : 0u) << c;
    }
#pragma unroll 8
    for (int c = 32; c < 64; ++c) {
        float4 v = *(const float4*)(px + (size_t)c * HW_);
        float sc = s_scale[c], bi = s_bias[c];
        hi0 |= (fmaf(v.x, sc, bi) < 0.0f ? 1u : 0u) << (c - 32);
        hi1 |= (fmaf(v.y, sc, bi) < 0.0f ? 1u : 0u) << (c - 32);
        hi2 |= (fmaf(v.z, sc, bi) < 0.0f ? 1u : 0u) << (c - 32);
        hi3 |= (fmaf(v.w, sc, bi) < 0.0f ? 1u : 0u) << (c - 32);
    }
    u64* dst = abits + (size_t)n * HW_ + (size_t)p4 * 4;
    ulonglong2 w01, w23;
    w01.x = (u64)lo0 | ((u64)hi0 << 32);
    w01.y = (u64)lo1 | ((u64)hi1 << 32);
    w23.x = (u64)lo2 | ((u64)hi2 << 32);
    w23.y = (u64)lo3 | ((u64)hi3 << 32);
    *(ulonglong2*)(dst)     = w01;
    *(ulonglong2*)(dst + 2) = w23;
}

struct Row { u64 a[6]; };

__device__ __forceinline__ void load_row(const u64* __restrict__ p,
                                         int om1, int o5, bool v0, bool v5,
                                         Row& r) {
    ulonglong2 x01 = *(const ulonglong2*)(p);
    ulonglong2 x23 = *(const ulonglong2*)(p + 2);
    u64 am = p[om1];
    u64 ap = p[o5];
    r.a[0] = v0 ? am : 0ull;
    r.a[1] = x01.x; r.a[2] = x01.y; r.a[3] = x23.x; r.a[4] = x23.y;
    r.a[5] = v5 ? ap : 0ull;
}

#define RACC(R, dh) do { \
    s0 += (int)(__popcll(R.a[0] ^ Wv9[3*dh+0]) + __popcll(R.a[1] ^ Wv9[3*dh+1]) + __popcll(R.a[2] ^ Wv9[3*dh+2])); \
    s1 += (int)(__popcll(R.a[1] ^ Wv9[3*dh+0]) + __popcll(R.a[2] ^ Wv9[3*dh+1]) + __popcll(R.a[3] ^ Wv9[3*dh+2])); \
    s2 += (int)(__popcll(R.a[2] ^ Wv9[3*dh+0]) + __popcll(R.a[3] ^ Wv9[3*dh+1]) + __popcll(R.a[4] ^ Wv9[3*dh+2])); \
    s3 += (int)(__popcll(R.a[3] ^ Wv9[3*dh+0]) + __popcll(R.a[4] ^ Wv9[3*dh+1]) + __popcll(R.a[5] ^ Wv9[3*dh+2])); \
  } while (0)

__global__ void k_conv(const float* __restrict__ x,
                       const u64* __restrict__ abits,
                       const float* __restrict__ weight,
                       const float* __restrict__ alpha,
                       float* __restrict__ out) {
    const int lane = threadIdx.x & 63;
    const int wid  = threadIdx.x >> 6;
    const int no = blockIdx.y;           // n*64 + o  (o wave-uniform)
    const int o  = no & 63;
    const int n  = no >> 6;

    // weight sign words via ballot: lane = input channel, one word per tap
    u64 Wv9[9];
    {
        const float* wp = weight + ((size_t)o * 64 + lane) * 9;
#pragma unroll
        for (int k = 0; k < 9; ++k)
            Wv9[k] = __ballot(wp[k] < 0.0f);
    }
    if (lane >= 56) return;

    const int h0 = (blockIdx.x * 4 + wid) * 8;   // 8 rows per wave
    const int w0 = lane * 4;
    const bool v0 = (lane != 0);
    const bool v5 = (lane != 55);
    const int om1 = v0 ? -1 : 0;
    const int o5  = v5 ? 4 : 3;

    int b0c[3], b3c[3];
#pragma unroll
    for (int d = 0; d < 3; ++d) {
        b0c[d] = v0 ? 192 : 128 + 2 * (int)__popcll(Wv9[3*d+0]);
        b3c[d] = v5 ? 192 : 128 + 2 * (int)__popcll(Wv9[3*d+2]);
    }
    const float al = alpha[o];
    const u64* An = abits + (size_t)n * HW_;
    size_t xoff = (size_t)no * HW_ + (size_t)h0 * 224 + w0;

    Row R[4];
    if (h0 != 0 && h0 != 216) {
        // ---- interior fast path: all 10 rows in-bounds, bases constant ----
        load_row(An + (size_t)(h0 - 1) * 224 + w0, om1, o5, v0, v5, R[0]);
        load_row(An + (size_t)(h0    ) * 224 + w0, om1, o5, v0, v5, R[1]);
        load_row(An + (size_t)(h0 + 1) * 224 + w0, om1, o5, v0, v5, R[2]);
        const int B0t = b0c[0] + b0c[1] + b0c[2];
        const int B3t = b3c[0] + b3c[1] + b3c[2];
#pragma unroll
        for (int hh = 0; hh < 8; ++hh) {
            if (hh < 7)
                load_row(An + (size_t)(h0 + hh + 2) * 224 + w0, om1, o5, v0, v5,
                         R[(hh + 3) & 3]);
            f32x4 xr = __builtin_nontemporal_load((const f32x4*)(x + xoff));
            Row& Rm = R[(hh + 0) & 3];
            Row& R0 = R[(hh + 1) & 3];
            Row& Rp = R[(hh + 2) & 3];
            int s0 = 0, s1 = 0, s2 = 0, s3 = 0;
            RACC(Rm, 0); RACC(R0, 1); RACC(Rp, 2);
            f32x4 yo;
            yo.x = fmaf(al, (float)(B0t - 2 * s0), xr.x);
            yo.y = fmaf(al, (float)(576 - 2 * s1), xr.y);
            yo.z = fmaf(al, (float)(576 - 2 * s2), xr.z);
            yo.w = fmaf(al, (float)(B3t - 2 * s3), xr.w);
            __builtin_nontemporal_store(yo, (f32x4*)(out + xoff));
            xoff += 224;
        }
    } else {
        // ---- edge strips (h0 == 0 or h0 == 216) ----
#pragma unroll
        for (int k = 0; k < 6; ++k) R[0].a[k] = 0ull;
        if (h0 > 0) load_row(An + (size_t)(h0 - 1) * 224 + w0, om1, o5, v0, v5, R[0]);
        load_row(An + (size_t)(h0    ) * 224 + w0, om1, o5, v0, v5, R[1]);
        load_row(An + (size_t)(h0 + 1) * 224 + w0, om1, o5, v0, v5, R[2]);
#pragma unroll
        for (int hh = 0; hh < 8; ++hh) {
            const int h = h0 + hh;
            if (hh < 7 && h + 2 <= 223)
                load_row(An + (size_t)(h + 2) * 224 + w0, om1, o5, v0, v5,
                         R[(hh + 3) & 3]);
            f32x4 xr = __builtin_nontemporal_load((const f32x4*)(x + xoff));
            Row& Rm = R[(hh + 0) & 3];
            Row& R0 = R[(hh + 1) & 3];
            Row& Rp = R[(hh + 2) & 3];
            int s0 = 0, s1 = 0, s2 = 0, s3 = 0, B0 = 0, B3 = 0, nb = 0;
            if (h > 0)   { RACC(Rm, 0); B0 += b0c[0]; B3 += b3c[0]; nb += 192; }
            { RACC(R0, 1); B0 += b0c[1]; B3 += b3c[1]; nb += 192; }
            if (h < 223) { RACC(Rp, 2); B0 += b0c[2]; B3 += b3c[2]; nb += 192; }
            f32x4 yo;
            yo.x = fmaf(al, (float)(B0 - 2 * s0), xr.x);
            yo.y = fmaf(al, (float)(nb - 2 * s1), xr.y);
            yo.z = fmaf(al, (float)(nb - 2 * s2), xr.z);
            yo.w = fmaf(al, (float)(B3 - 2 * s3), xr.w);
            __builtin_nontemporal_store(yo, (f32x4*)(out + xoff));
            xoff += 224;
        }
    }
}

extern "C" void kernel_launch(void* const* d_in, const int* in_sizes, int n_in,
                              void* d_out, int out_size, void* d_ws, size_t ws_size,
                              hipStream_t stream) {
    const float* x      = (const float*)d_in[0];
    const float* gamma  = (const float*)d_in[1];
    const float* beta   = (const float*)d_in[2];
    const float* weight = (const float*)d_in[3];
    const float* alpha  = (const float*)d_in[4];
    float* out = (float*)d_out;

    char* ws = (char*)d_ws;
    double2* part  = (double2*)(ws + 0);
    u64*     abits = (u64*)(ws + 32768);

    k_stats   <<<N_ * C_, 256, 0, stream>>>(x, part);
    k_binpack <<<dim3((HW_ / 4) / 256, N_), 256, 0, stream>>>(x, part, gamma, beta, abits);
    k_conv    <<<dim3(7, 1024), 256, 0, stream>>>(x, abits, weight, alpha, out);
}

// Round 6
// 149.844 us; speedup vs baseline: 1.0646x; 1.0646x over previous
//
#include <hip/hip_runtime.h>
#include <cstdint>
#include <cstddef>

#define N_  16
#define C_  64
#define H_  224
#define W_  224
#define HW_ (H_ * W_)      // 50176
#define NHW_ (N_ * HW_)    // 802816

typedef unsigned long long u64;
typedef float f32x4 __attribute__((ext_vector_type(4)));

// ---------------------------------------------------------------------------
// ws layout (bytes):
//   [0,      16384) double2 part[64*16]   per-(c,n) partial {sum, sumsq}
//   [32768, +6.4MB) u64   abits[16*50176] activation sign bits packed over C
// ---------------------------------------------------------------------------

__global__ void k_stats(const float* __restrict__ x, double2* __restrict__ part) {
    int b = blockIdx.x;          // (n,c)
    int c = b & 63;
    int n = b >> 6;
    const float4* px = (const float4*)(x + (size_t)(n * 64 + c) * HW_);
    double s = 0.0, ss = 0.0;
    for (int i = threadIdx.x; i < HW_ / 4; i += 256) {
        float4 v = px[i];
        s  += (double)v.x + (double)v.y + (double)v.z + (double)v.w;
        ss += (double)v.x * v.x + (double)v.y * v.y
            + (double)v.z * v.z + (double)v.w * v.w;
    }
    __shared__ double sh_s[256];
    __shared__ double sh_q[256];
    sh_s[threadIdx.x] = s;
    sh_q[threadIdx.x] = ss;
    __syncthreads();
    for (int off = 128; off > 0; off >>= 1) {
        if (threadIdx.x < (unsigned)off) {
            sh_s[threadIdx.x] += sh_s[threadIdx.x + off];
            sh_q[threadIdx.x] += sh_q[threadIdx.x + off];
        }
        __syncthreads();
    }
    if (threadIdx.x == 0) part[c * 16 + n] = make_double2(sh_s[0], sh_q[0]);
}

// one thread = 4 consecutive spatial positions, all 64 channels.
// scale/bias computed inline from part (no finalize kernel).
__global__ void k_binpack(const float* __restrict__ x,
                          const double2* __restrict__ part,
                          const float* __restrict__ gamma,
                          const float* __restrict__ beta,
                          u64* __restrict__ abits) {
    __shared__ float s_scale[64];
    __shared__ float s_bias[64];
    int t = threadIdx.x;
    if (t < 64) {
        double s = 0.0, ss = 0.0;
#pragma unroll
        for (int nn = 0; nn < 16; ++nn) {
            double2 p = part[t * 16 + nn];
            s += p.x; ss += p.y;
        }
        double mean = s / (double)NHW_;
        double var  = ss / (double)NHW_ - mean * mean;
        double inv  = 1.0 / sqrt(var + 1e-5);
        double g    = (double)gamma[t];
        s_scale[t] = (float)(g * inv);
        s_bias[t]  = (float)((double)beta[t] - mean * g * inv);
    }
    __syncthreads();
    int p4 = blockIdx.x * 256 + t;             // quad within image, 0..12543
    int n  = blockIdx.y;
    const float* px = x + (size_t)n * 64 * HW_ + (size_t)p4 * 4;

    unsigned lo0 = 0, lo1 = 0, lo2 = 0, lo3 = 0;
    unsigned hi0 = 0, hi1 = 0, hi2 = 0, hi3 = 0;
#pragma unroll 8
    for (int c = 0; c < 32; ++c) {
        float4 v = *(const float4*)(px + (size_t)c * HW_);
        float sc = s_scale[c], bi = s_bias[c];
        lo0 |= (fmaf(v.x, sc, bi) < 0.0f ? 1u : 0u) << c;
        lo1 |= (fmaf(v.y, sc, bi) < 0.0f ? 1u : 0u) << c;
        lo2 |= (fmaf(v.z, sc, bi) < 0.0f ? 1u : 0u) << c;
        lo3 |= (fmaf(v.w, sc, bi) < 0.0f ? 1u : 0u) << c;
    }
#pragma unroll 8
    for (int c = 32; c < 64; ++c) {
        float4 v = *(const float4*)(px + (size_t)c * HW_);
        float sc = s_scale[c], bi = s_bias[c];
        hi0 |= (fmaf(v.x, sc, bi) < 0.0f ? 1u : 0u) << (c - 32);
        hi1 |= (fmaf(v.y, sc, bi) < 0.0f ? 1u : 0u) << (c - 32);
        hi2 |= (fmaf(v.z, sc, bi) < 0.0f ? 1u : 0u) << (c - 32);
        hi3 |= (fmaf(v.w, sc, bi) < 0.0f ? 1u : 0u) << (c - 32);
    }
    u64* dst = abits + (size_t)n * HW_ + (size_t)p4 * 4;
    ulonglong2 w01, w23;
    w01.x = (u64)lo0 | ((u64)hi0 << 32);
    w01.y = (u64)lo1 | ((u64)hi1 << 32);
    w23.x = (u64)lo2 | ((u64)hi2 << 32);
    w23.y = (u64)lo3 | ((u64)hi3 << 32);
    *(ulonglong2*)(dst)     = w01;
    *(ulonglong2*)(dst + 2) = w23;
}

struct Row { u64 a[6]; };

__device__ __forceinline__ void load_row(const u64* __restrict__ p,
                                         int om1, int o5, bool v0, bool v5,
                                         Row& r) {
    ulonglong2 x01 = *(const ulonglong2*)(p);
    ulonglong2 x23 = *(const ulonglong2*)(p + 2);
    u64 am = p[om1];
    u64 ap = p[o5];
    r.a[0] = v0 ? am : 0ull;
    r.a[1] = x01.x; r.a[2] = x01.y; r.a[3] = x23.x; r.a[4] = x23.y;
    r.a[5] = v5 ? ap : 0ull;
}

#define RACC(R, dh) do { \
    s0 += (int)(__popcll(R.a[0] ^ Wv9[3*dh+0]) + __popcll(R.a[1] ^ Wv9[3*dh+1]) + __popcll(R.a[2] ^ Wv9[3*dh+2])); \
    s1 += (int)(__popcll(R.a[1] ^ Wv9[3*dh+0]) + __popcll(R.a[2] ^ Wv9[3*dh+1]) + __popcll(R.a[3] ^ Wv9[3*dh+2])); \
    s2 += (int)(__popcll(R.a[2] ^ Wv9[3*dh+0]) + __popcll(R.a[3] ^ Wv9[3*dh+1]) + __popcll(R.a[4] ^ Wv9[3*dh+2])); \
    s3 += (int)(__popcll(R.a[3] ^ Wv9[3*dh+0]) + __popcll(R.a[4] ^ Wv9[3*dh+1]) + __popcll(R.a[5] ^ Wv9[3*dh+2])); \
  } while (0)

__global__ void k_conv(const float* __restrict__ x,
                       const u64* __restrict__ abits,
                       const float* __restrict__ weight,
                       const float* __restrict__ alpha,
                       float* __restrict__ out) {
    const int lane = threadIdx.x & 63;
    const int wid  = threadIdx.x >> 6;
    // reversed n-order: binpack left high-n slabs warmest in L3 LRU
    const int no = 1023 - blockIdx.y;    // n*64 + o  (o wave-uniform)
    const int o  = no & 63;
    const int n  = no >> 6;

    // weight sign words via ballot: lane = input channel, one word per tap
    u64 Wv9[9];
    {
        const float* wp = weight + ((size_t)o * 64 + lane) * 9;
#pragma unroll
        for (int k = 0; k < 9; ++k)
            Wv9[k] = __ballot(wp[k] < 0.0f);
    }
    if (lane >= 56) return;

    const int h0 = (blockIdx.x * 4 + wid) * 8;   // 8 rows per wave
    const int w0 = lane * 4;
    const bool v0 = (lane != 0);
    const bool v5 = (lane != 55);
    const int om1 = v0 ? -1 : 0;
    const int o5  = v5 ? 4 : 3;

    int b0c[3], b3c[3];
#pragma unroll
    for (int d = 0; d < 3; ++d) {
        b0c[d] = v0 ? 192 : 128 + 2 * (int)__popcll(Wv9[3*d+0]);
        b3c[d] = v5 ? 192 : 128 + 2 * (int)__popcll(Wv9[3*d+2]);
    }
    const float al = alpha[o];
    const u64* An = abits + (size_t)n * HW_;
    size_t xoff = (size_t)no * HW_ + (size_t)h0 * 224 + w0;

    Row R[4];
    if (h0 != 0 && h0 != 216) {
        // ---- interior fast path: all 10 rows in-bounds, bases constant ----
        load_row(An + (size_t)(h0 - 1) * 224 + w0, om1, o5, v0, v5, R[0]);
        load_row(An + (size_t)(h0    ) * 224 + w0, om1, o5, v0, v5, R[1]);
        load_row(An + (size_t)(h0 + 1) * 224 + w0, om1, o5, v0, v5, R[2]);
        const int B0t = b0c[0] + b0c[1] + b0c[2];
        const int B3t = b3c[0] + b3c[1] + b3c[2];
        f32x4 xr_cur = *(const f32x4*)(x + xoff);          // row 0 residual
#pragma unroll
        for (int hh = 0; hh < 8; ++hh) {
            if (hh < 7)
                load_row(An + (size_t)(h0 + hh + 2) * 224 + w0, om1, o5, v0, v5,
                         R[(hh + 3) & 3]);
            f32x4 xr_nxt;
            if (hh < 7) xr_nxt = *(const f32x4*)(x + xoff + 224);  // prefetch next row
            Row& Rm = R[(hh + 0) & 3];
            Row& R0 = R[(hh + 1) & 3];
            Row& Rp = R[(hh + 2) & 3];
            int s0 = 0, s1 = 0, s2 = 0, s3 = 0;
            RACC(Rm, 0); RACC(R0, 1); RACC(Rp, 2);
            f32x4 yo;
            yo.x = fmaf(al, (float)(B0t - 2 * s0), xr_cur.x);
            yo.y = fmaf(al, (float)(576 - 2 * s1), xr_cur.y);
            yo.z = fmaf(al, (float)(576 - 2 * s2), xr_cur.z);
            yo.w = fmaf(al, (float)(B3t - 2 * s3), xr_cur.w);
            __builtin_nontemporal_store(yo, (f32x4*)(out + xoff));
            xr_cur = xr_nxt;
            xoff += 224;
        }
    } else {
        // ---- edge strips (h0 == 0 or h0 == 216) ----
#pragma unroll
        for (int k = 0; k < 6; ++k) R[0].a[k] = 0ull;
        if (h0 > 0) load_row(An + (size_t)(h0 - 1) * 224 + w0, om1, o5, v0, v5, R[0]);
        load_row(An + (size_t)(h0    ) * 224 + w0, om1, o5, v0, v5, R[1]);
        load_row(An + (size_t)(h0 + 1) * 224 + w0, om1, o5, v0, v5, R[2]);
        f32x4 xr_cur = *(const f32x4*)(x + xoff);
#pragma unroll
        for (int hh = 0; hh < 8; ++hh) {
            const int h = h0 + hh;
            if (hh < 7 && h + 2 <= 223)
                load_row(An + (size_t)(h + 2) * 224 + w0, om1, o5, v0, v5,
                         R[(hh + 3) & 3]);
            f32x4 xr_nxt;
            if (hh < 7) xr_nxt = *(const f32x4*)(x + xoff + 224);
            Row& Rm = R[(hh + 0) & 3];
            Row& R0 = R[(hh + 1) & 3];
            Row& Rp = R[(hh + 2) & 3];
            int s0 = 0, s1 = 0, s2 = 0, s3 = 0, B0 = 0, B3 = 0, nb = 0;
            if (h > 0)   { RACC(Rm, 0); B0 += b0c[0]; B3 += b3c[0]; nb += 192; }
            { RACC(R0, 1); B0 += b0c[1]; B3 += b3c[1]; nb += 192; }
            if (h < 223) { RACC(Rp, 2); B0 += b0c[2]; B3 += b3c[2]; nb += 192; }
            f32x4 yo;
            yo.x = fmaf(al, (float)(B0 - 2 * s0), xr_cur.x);
            yo.y = fmaf(al, (float)(nb - 2 * s1), xr_cur.y);
            yo.z = fmaf(al, (float)(nb - 2 * s2), xr_cur.z);
            yo.w = fmaf(al, (float)(B3 - 2 * s3), xr_cur.w);
            __builtin_nontemporal_store(yo, (f32x4*)(out + xoff));
            xr_cur = xr_nxt;
            xoff += 224;
        }
    }
}

extern "C" void kernel_launch(void* const* d_in, const int* in_sizes, int n_in,
                              void* d_out, int out_size, void* d_ws, size_t ws_size,
                              hipStream_t stream) {
    const float* x      = (const float*)d_in[0];
    const float* gamma  = (const float*)d_in[1];
    const float* beta   = (const float*)d_in[2];
    const float* weight = (const float*)d_in[3];
    const float* alpha  = (const float*)d_in[4];
    float* out = (float*)d_out;

    char* ws = (char*)d_ws;
    double2* part  = (double2*)(ws + 0);
    u64*     abits = (u64*)(ws + 32768);

    k_stats   <<<N_ * C_, 256, 0, stream>>>(x, part);
    k_binpack <<<dim3((HW_ / 4) / 256, N_), 256, 0, stream>>>(x, part, gamma, beta, abits);
    k_conv    <<<dim3(7, 1024), 256, 0, stream>>>(x, abits, weight, alpha, out);
}

// Round 7
// 147.388 us; speedup vs baseline: 1.0824x; 1.0167x over previous
//
#include <hip/hip_runtime.h>
#include <cstdint>
#include <cstddef>

#define N_  16
#define C_  64
#define H_  224
#define W_  224
#define HW_ (H_ * W_)      // 50176
#define NHW_ (N_ * HW_)    // 802816

typedef unsigned long long u64;
typedef float f32x4 __attribute__((ext_vector_type(4)));

// ---------------------------------------------------------------------------
// ws layout (bytes):
//   [0,      16384) double2 part[64*16]   per-(c,n) partial {sum, sumsq}
//   [32768, +6.4MB) u64   abits[16*50176] activation sign bits packed over C
// ---------------------------------------------------------------------------

__global__ void k_stats(const float* __restrict__ x, double2* __restrict__ part) {
    int b = blockIdx.x;          // (n,c)
    int c = b & 63;
    int n = b >> 6;
    const float4* px = (const float4*)(x + (size_t)(n * 64 + c) * HW_);
    double s = 0.0, ss = 0.0;
    for (int i = threadIdx.x; i < HW_ / 4; i += 256) {
        float4 v = px[i];
        s  += (double)v.x + (double)v.y + (double)v.z + (double)v.w;
        ss += (double)v.x * v.x + (double)v.y * v.y
            + (double)v.z * v.z + (double)v.w * v.w;
    }
    __shared__ double sh_s[256];
    __shared__ double sh_q[256];
    sh_s[threadIdx.x] = s;
    sh_q[threadIdx.x] = ss;
    __syncthreads();
    for (int off = 128; off > 0; off >>= 1) {
        if (threadIdx.x < (unsigned)off) {
            sh_s[threadIdx.x] += sh_s[threadIdx.x + off];
            sh_q[threadIdx.x] += sh_q[threadIdx.x + off];
        }
        __syncthreads();
    }
    if (threadIdx.x == 0) part[c * 16 + n] = make_double2(sh_s[0], sh_q[0]);
}

// one thread = 4 consecutive spatial positions, all 64 channels.
__global__ void k_binpack(const float* __restrict__ x,
                          const double2* __restrict__ part,
                          const float* __restrict__ gamma,
                          const float* __restrict__ beta,
                          u64* __restrict__ abits) {
    __shared__ float s_scale[64];
    __shared__ float s_bias[64];
    int t = threadIdx.x;
    if (t < 64) {
        double s = 0.0, ss = 0.0;
#pragma unroll
        for (int nn = 0; nn < 16; ++nn) {
            double2 p = part[t * 16 + nn];
            s += p.x; ss += p.y;
        }
        double mean = s / (double)NHW_;
        double var  = ss / (double)NHW_ - mean * mean;
        double inv  = 1.0 / sqrt(var + 1e-5);
        double g    = (double)gamma[t];
        s_scale[t] = (float)(g * inv);
        s_bias[t]  = (float)((double)beta[t] - mean * g * inv);
    }
    __syncthreads();
    int p4 = blockIdx.x * 256 + t;             // quad within image, 0..12543
    int n  = blockIdx.y;
    const float* px = x + (size_t)n * 64 * HW_ + (size_t)p4 * 4;

    unsigned lo0 = 0, lo1 = 0, lo2 = 0, lo3 = 0;
    unsigned hi0 = 0, hi1 = 0, hi2 = 0, hi3 = 0;
#pragma unroll 8
    for (int c = 0; c < 32; ++c) {
        float4 v = *(const float4*)(px + (size_t)c * HW_);
        float sc = s_scale[c], bi = s_bias[c];
        lo0 |= (fmaf(v.x, sc, bi) < 0.0f ? 1u : 0u) << c;
        lo1 |= (fmaf(v.y, sc, bi) < 0.0f ? 1u : 0u) << c;
        lo2 |= (fmaf(v.z, sc, bi) < 0.0f ? 1u : 0u) << c;
        lo3 |= (fmaf(v.w, sc, bi) < 0.0f ? 1u : 0u) << c;
    }
#pragma unroll 8
    for (int c = 32; c < 64; ++c) {
        float4 v = *(const float4*)(px + (size_t)c * HW_);
        float sc = s_scale[c], bi = s_bias[c];
        hi0 |= (fmaf(v.x, sc, bi) < 0.0f ? 1u : 0u) << (c - 32);
        hi1 |= (fmaf(v.y, sc, bi) < 0.0f ? 1u : 0u) << (c - 32);
        hi2 |= (fmaf(v.z, sc, bi) < 0.0f ? 1u : 0u) << (c - 32);
        hi3 |= (fmaf(v.w, sc, bi) < 0.0f ? 1u : 0u) << (c - 32);
    }
    u64* dst = abits + (size_t)n * HW_ + (size_t)p4 * 4;
    ulonglong2 w01, w23;
    w01.x = (u64)lo0 | ((u64)hi0 << 32);
    w01.y = (u64)lo1 | ((u64)hi1 << 32);
    w23.x = (u64)lo2 | ((u64)hi2 << 32);
    w23.y = (u64)lo3 | ((u64)hi3 << 32);
    *(ulonglong2*)(dst)     = w01;
    *(ulonglong2*)(dst + 2) = w23;
}

// ---------------- conv helpers ----------------
// interior fast path: halos via cross-lane shuffle, only 2 VMEM per A-row
struct RowM { u64 m0, m1, m2, m3, a0, a5; };

__device__ __forceinline__ void load_main(const u64* __restrict__ p, RowM& r) {
    ulonglong2 x01 = *(const ulonglong2*)(p);
    ulonglong2 x23 = *(const ulonglong2*)(p + 2);
    r.m0 = x01.x; r.m1 = x01.y; r.m2 = x23.x; r.m3 = x23.y;
}

// lane L's a0 (word w0-1) = lane L-1's m3; a5 (word w0+4) = lane L+1's m0.
__device__ __forceinline__ void make_halo(RowM& r, bool v0, bool v5) {
    u64 up = __shfl_up(r.m3, 1);
    u64 dn = __shfl_down(r.m0, 1);
    r.a0 = v0 ? up : 0ull;
    r.a5 = v5 ? dn : 0ull;
}

#define RACCM(R, dh) do { \
    s0 += (int)(__popcll(R.a0 ^ Wv9[3*dh+0]) + __popcll(R.m0 ^ Wv9[3*dh+1]) + __popcll(R.m1 ^ Wv9[3*dh+2])); \
    s1 += (int)(__popcll(R.m0 ^ Wv9[3*dh+0]) + __popcll(R.m1 ^ Wv9[3*dh+1]) + __popcll(R.m2 ^ Wv9[3*dh+2])); \
    s2 += (int)(__popcll(R.m1 ^ Wv9[3*dh+0]) + __popcll(R.m2 ^ Wv9[3*dh+1]) + __popcll(R.m3 ^ Wv9[3*dh+2])); \
    s3 += (int)(__popcll(R.m2 ^ Wv9[3*dh+0]) + __popcll(R.m3 ^ Wv9[3*dh+1]) + __popcll(R.a5 ^ Wv9[3*dh+2])); \
  } while (0)

// edge path (cold): old 6-word rows with clamped scalar halo loads
struct Row { u64 a[6]; };

__device__ __forceinline__ void load_row(const u64* __restrict__ p,
                                         int om1, int o5, bool v0, bool v5,
                                         Row& r) {
    ulonglong2 x01 = *(const ulonglong2*)(p);
    ulonglong2 x23 = *(const ulonglong2*)(p + 2);
    u64 am = p[om1];
    u64 ap = p[o5];
    r.a[0] = v0 ? am : 0ull;
    r.a[1] = x01.x; r.a[2] = x01.y; r.a[3] = x23.x; r.a[4] = x23.y;
    r.a[5] = v5 ? ap : 0ull;
}

#define RACC(R, dh) do { \
    s0 += (int)(__popcll(R.a[0] ^ Wv9[3*dh+0]) + __popcll(R.a[1] ^ Wv9[3*dh+1]) + __popcll(R.a[2] ^ Wv9[3*dh+2])); \
    s1 += (int)(__popcll(R.a[1] ^ Wv9[3*dh+0]) + __popcll(R.a[2] ^ Wv9[3*dh+1]) + __popcll(R.a[3] ^ Wv9[3*dh+2])); \
    s2 += (int)(__popcll(R.a[2] ^ Wv9[3*dh+0]) + __popcll(R.a[3] ^ Wv9[3*dh+1]) + __popcll(R.a[4] ^ Wv9[3*dh+2])); \
    s3 += (int)(__popcll(R.a[3] ^ Wv9[3*dh+0]) + __popcll(R.a[4] ^ Wv9[3*dh+1]) + __popcll(R.a[5] ^ Wv9[3*dh+2])); \
  } while (0)

__global__ void k_conv(const float* __restrict__ x,
                       const u64* __restrict__ abits,
                       const float* __restrict__ weight,
                       const float* __restrict__ alpha,
                       float* __restrict__ out) {
    const int lane = threadIdx.x & 63;
    const int wid  = threadIdx.x >> 6;
    // reversed n-order: binpack left high-n slabs warmest in L3 LRU
    const int no = 1023 - blockIdx.y;    // n*64 + o  (o wave-uniform)
    const int o  = no & 63;
    const int n  = no >> 6;

    // weight sign words via ballot: lane = input channel, one word per tap
    u64 Wv9[9];
    {
        const float* wp = weight + ((size_t)o * 64 + lane) * 9;
#pragma unroll
        for (int k = 0; k < 9; ++k)
            Wv9[k] = __ballot(wp[k] < 0.0f);
    }
    if (lane >= 56) return;

    const int h0 = (blockIdx.x * 4 + wid) * 8;   // 8 rows per wave
    const int w0 = lane * 4;
    const bool v0 = (lane != 0);
    const bool v5 = (lane != 55);

    int b0c[3], b3c[3];
#pragma unroll
    for (int d = 0; d < 3; ++d) {
        b0c[d] = v0 ? 192 : 128 + 2 * (int)__popcll(Wv9[3*d+0]);
        b3c[d] = v5 ? 192 : 128 + 2 * (int)__popcll(Wv9[3*d+2]);
    }
    const float al = alpha[o];
    const u64* An = abits + (size_t)n * HW_;
    size_t xoff = (size_t)no * HW_ + (size_t)h0 * 224 + w0;

    if (h0 != 0 && h0 != 216) {
        // ---- interior fast path: rows h0-1..h0+8 all in-bounds ----
        RowM Q[5];
        const u64* base = An + (size_t)(h0 - 1) * 224 + w0;
        load_main(base + 0 * 224, Q[0]);
        load_main(base + 1 * 224, Q[1]);
        load_main(base + 2 * 224, Q[2]);
        load_main(base + 3 * 224, Q[3]);
        make_halo(Q[0], v0, v5);
        make_halo(Q[1], v0, v5);
        f32x4 xq[3];
        xq[0] = *(const f32x4*)(x + xoff);
        xq[1] = *(const f32x4*)(x + xoff + 224);
        const int B0t = b0c[0] + b0c[1] + b0c[2];
        const int B3t = b3c[0] + b3c[1] + b3c[2];
#pragma unroll
        for (int hh = 0; hh < 8; ++hh) {
            // prefetch A-row h0+hh+3 (k=hh+4), used 2 iterations later
            if (hh <= 5)
                load_main(base + (size_t)(hh + 4) * 224, Q[(hh + 4) % 5]);
            // residual prefetch, 2 rows ahead
            if (hh < 6)
                xq[(hh + 2) % 3] = *(const f32x4*)(x + xoff + 448);
            // first use of row k=hh+2: build halos now (its load is 2 iters old)
            make_halo(Q[(hh + 2) % 5], v0, v5);
            RowM& Rm = Q[(hh + 0) % 5];
            RowM& R0 = Q[(hh + 1) % 5];
            RowM& Rp = Q[(hh + 2) % 5];
            int s0 = 0, s1 = 0, s2 = 0, s3 = 0;
            RACCM(Rm, 0); RACCM(R0, 1); RACCM(Rp, 2);
            f32x4 xr = xq[hh % 3];
            f32x4 yo;
            yo.x = fmaf(al, (float)(B0t - 2 * s0), xr.x);
            yo.y = fmaf(al, (float)(576 - 2 * s1), xr.y);
            yo.z = fmaf(al, (float)(576 - 2 * s2), xr.z);
            yo.w = fmaf(al, (float)(B3t - 2 * s3), xr.w);
            __builtin_nontemporal_store(yo, (f32x4*)(out + xoff));
            xoff += 224;
        }
    } else {
        // ---- edge strips (h0 == 0 or h0 == 216), cold path ----
        const int om1 = v0 ? -1 : 0;
        const int o5  = v5 ? 4 : 3;
        Row R[4];
#pragma unroll
        for (int k = 0; k < 6; ++k) R[0].a[k] = 0ull;
        if (h0 > 0) load_row(An + (size_t)(h0 - 1) * 224 + w0, om1, o5, v0, v5, R[0]);
        load_row(An + (size_t)(h0    ) * 224 + w0, om1, o5, v0, v5, R[1]);
        load_row(An + (size_t)(h0 + 1) * 224 + w0, om1, o5, v0, v5, R[2]);
        f32x4 xr_cur = *(const f32x4*)(x + xoff);
#pragma unroll
        for (int hh = 0; hh < 8; ++hh) {
            const int h = h0 + hh;
            if (hh < 7 && h + 2 <= 223)
                load_row(An + (size_t)(h + 2) * 224 + w0, om1, o5, v0, v5,
                         R[(hh + 3) & 3]);
            f32x4 xr_nxt;
            if (hh < 7) xr_nxt = *(const f32x4*)(x + xoff + 224);
            Row& Rm = R[(hh + 0) & 3];
            Row& R0 = R[(hh + 1) & 3];
            Row& Rp = R[(hh + 2) & 3];
            int s0 = 0, s1 = 0, s2 = 0, s3 = 0, B0 = 0, B3 = 0, nb = 0;
            if (h > 0)   { RACC(Rm, 0); B0 += b0c[0]; B3 += b3c[0]; nb += 192; }
            { RACC(R0, 1); B0 += b0c[1]; B3 += b3c[1]; nb += 192; }
            if (h < 223) { RACC(Rp, 2); B0 += b0c[2]; B3 += b3c[2]; nb += 192; }
            f32x4 yo;
            yo.x = fmaf(al, (float)(B0 - 2 * s0), xr_cur.x);
            yo.y = fmaf(al, (float)(nb - 2 * s1), xr_cur.y);
            yo.z = fmaf(al, (float)(nb - 2 * s2), xr_cur.z);
            yo.w = fmaf(al, (float)(B3 - 2 * s3), xr_cur.w);
            __builtin_nontemporal_store(yo, (f32x4*)(out + xoff));
            xr_cur = xr_nxt;
            xoff += 224;
        }
    }
}

extern "C" void kernel_launch(void* const* d_in, const int* in_sizes, int n_in,
                              void* d_out, int out_size, void* d_ws, size_t ws_size,
                              hipStream_t stream) {
    const float* x      = (const float*)d_in[0];
    const float* gamma  = (const float*)d_in[1];
    const float* beta   = (const float*)d_in[2];
    const float* weight = (const float*)d_in[3];
    const float* alpha  = (const float*)d_in[4];
    float* out = (float*)d_out;

    char* ws = (char*)d_ws;
    double2* part  = (double2*)(ws + 0);
    u64*     abits = (u64*)(ws + 32768);

    k_stats   <<<N_ * C_, 256, 0, stream>>>(x, part);
    k_binpack <<<dim3((HW_ / 4) / 256, N_), 256, 0, stream>>>(x, part, gamma, beta, abits);
    k_conv    <<<dim3(7, 1024), 256, 0, stream>>>(x, abits, weight, alpha, out);
}